// Round 3
// baseline (177.921 us; speedup 1.0000x reference)
//
#include <hip/hip_runtime.h>

#define TDIM 128

__host__ __device__ inline int trivalid(int l, int l1, int l2) {
  int d = l1 - l2; if (d < 0) d = -d;
  return (l >= d && l <= l1 + l2) ? 1 : 0;
}

__device__ __forceinline__ float u2f(unsigned int u) {
  union { unsigned int u; float f; } w; w.u = u; return w.f;
}
__device__ __forceinline__ float bf2f(unsigned short v) {
  return u2f(((unsigned int)v) << 16);
}
__device__ __forceinline__ unsigned short f2bf(float x) {
  union { float f; unsigned int u; } w; w.f = x;
  unsigned int u = w.u;
  u += 0x7fffu + ((u >> 16) & 1u);   // round-to-nearest-even
  return (unsigned short)(u >> 16);
}

// One block per output row. Row r -> (l, m, pair p=(l1,l2));
// out[r*16384 + t1*128 + t2] = sum_{m1} C[k,i,j] * clms[i,t1] * clms[j,t2]
// Input/output dtype (f32 vs bf16) detected at runtime from the data itself
// (uniform decision -> scalar branches, identical every call, graph-safe).
__global__ __launch_bounds__(256, 2)
void cg_kernel(const void* __restrict__ clms_raw,
               const void* __restrict__ C_raw,
               void* __restrict__ out_raw) {
  __shared__ float sc[64 * TDIM];   // 32 KB: full clms upcast/copied to f32
  __shared__ float scoef[16];

  const int tid = threadIdx.x;

  // ---- dtype sniff (same result in every thread/block) ----
  // bf16 N(0,1) data: low 16 bits of each u32 word are a bf16 with exponent
  // field in ~[110,135]. f32 data: those bits are random mantissa (~10% hit).
  const unsigned int* cw = (const unsigned int*)clms_raw;
  int cnt_bf = 0;
  #pragma unroll
  for (int i = 0; i < 32; ++i) {
    unsigned int e = (cw[i] >> 7) & 0xFFu;
    cnt_bf += (e >= 110u && e <= 135u) ? 1 : 0;
  }
  const bool in_bf16 = (cnt_bf >= 16);
  // C[0] = <0 0 0 0|0 0> = 1.0 exactly: low half 0x3f80 iff bf16.
  const bool c_bf16 = ((*(const unsigned int*)C_raw) & 0xffffu) == 0x3f80u;

  if (tid < 16) scoef[tid] = 0.0f;

  // ---- stage clms into LDS as f32 ----
  if (in_bf16) {
    const uint4* cl4 = (const uint4*)clms_raw;   // 8192 bf16 = 1024 uint4
    #pragma unroll
    for (int it = 0; it < 4; ++it) {
      int v = tid + it * 256;
      uint4 w = cl4[v];
      float4* dst = (float4*)&sc[v * 8];
      float4 d0, d1;
      d0.x = u2f(w.x << 16); d0.y = u2f(w.x & 0xffff0000u);
      d0.z = u2f(w.y << 16); d0.w = u2f(w.y & 0xffff0000u);
      d1.x = u2f(w.z << 16); d1.y = u2f(w.z & 0xffff0000u);
      d1.z = u2f(w.w << 16); d1.w = u2f(w.w & 0xffff0000u);
      dst[0] = d0; dst[1] = d1;
    }
  } else {
    const float4* cf4 = (const float4*)clms_raw; // 8192 f32 = 2048 float4
    float4* sc4 = (float4*)sc;
    #pragma unroll
    for (int it = 0; it < 8; ++it) {
      int v = tid + it * 256;
      sc4[v] = cf4[v];
    }
  }

  // ---- decode blockIdx -> (l, m, l1, l2); uniform ----
  const int r = blockIdx.x;
  int rem = r, l = 0, cnt = 0;
  for (l = 0; l < 8; ++l) {
    cnt = 0;
    for (int a = 0; a < 8; ++a)
      for (int b = 0; b < 8; ++b) cnt += trivalid(l, a, b);
    int rows = (2 * l + 1) * cnt;
    if (rem < rows) break;
    rem -= rows;
  }
  const int mi = rem / cnt;          // m + l
  const int p  = rem - mi * cnt;     // pair index (l1-major order)
  const int m  = mi - l;
  int l1 = 0, l2 = 0;
  {
    int q = 0; bool done = false;
    for (int a = 0; a < 8 && !done; ++a)
      for (int b = 0; b < 8; ++b) {
        if (trivalid(l, a, b)) {
          if (q == p) { l1 = a; l2 = b; done = true; break; }
          ++q;
        }
      }
  }

  int m1lo = (-l1 > m - l2) ? -l1 : (m - l2);
  int m1hi = ( l1 < m + l2) ?  l1 : (m + l2);
  const int nnz = m1hi - m1lo + 1;   // 1..15

  // ---- stage CG coefficients for this row ----
  if (tid < nnz) {
    int m1 = m1lo + tid;
    int m2 = m - m1;
    int i  = l1 * (l1 + 1) + m1;
    int j  = l2 * (l2 + 1) + m2;
    int k  = l  * (l  + 1) + m;
    int ci = ((k * 64) + i) * 64 + j;
    scoef[tid] = c_bf16 ? bf2f(((const unsigned short*)C_raw)[ci])
                        : ((const float*)C_raw)[ci];
  }
  __syncthreads();

  float creg[15];
  #pragma unroll
  for (int q = 0; q < 15; ++q) creg[q] = scoef[q];   // q>=nnz -> 0.0f

  const int tx = tid & 31;
  const int ty = tid >> 5;
  const int t2 = tx * 4;
  const int i0 = l1 * (l1 + 1) + m1lo;           // A rows: i0+q
  const int j0 = l2 * (l2 + 1) + m - m1lo;       // B rows: j0-q

  // Precompute CLAMPED row offsets so any access (even speculated) is in-range.
  int arow[15], brow[15];
  #pragma unroll
  for (int q = 0; q < 15; ++q) {
    int qc = (q < nnz) ? q : 0;
    arow[q] = (i0 + qc) * TDIM;
    brow[q] = (j0 - qc) * TDIM;
  }

  float4 b[15];
  #pragma unroll
  for (int q = 0; q < 15; ++q) b[q] = *(const float4*)&sc[brow[q] + t2];

  const unsigned long long outbase = (unsigned long long)r * (TDIM * TDIM);

  if (in_bf16) {
    unsigned short* out = (unsigned short*)out_raw;
    #pragma unroll 4
    for (int s = 0; s < 16; ++s) {
      const int t1 = ty + 8 * s;
      float4 acc = make_float4(0.f, 0.f, 0.f, 0.f);
      #pragma unroll
      for (int q = 0; q < 15; ++q) {
        if (q < nnz) {                    // nnz uniform -> scalar branch
          float ca = creg[q] * sc[arow[q] + t1];
          acc.x += ca * b[q].x;  acc.y += ca * b[q].y;
          acc.z += ca * b[q].z;  acc.w += ca * b[q].w;
        }
      }
      ushort4 o;
      o.x = f2bf(acc.x); o.y = f2bf(acc.y);
      o.z = f2bf(acc.z); o.w = f2bf(acc.w);
      *(ushort4*)(out + outbase + (unsigned long long)(t1 * TDIM + t2)) = o;
    }
  } else {
    float* out = (float*)out_raw;
    #pragma unroll 4
    for (int s = 0; s < 16; ++s) {
      const int t1 = ty + 8 * s;
      float4 acc = make_float4(0.f, 0.f, 0.f, 0.f);
      #pragma unroll
      for (int q = 0; q < 15; ++q) {
        if (q < nnz) {
          float ca = creg[q] * sc[arow[q] + t1];
          acc.x += ca * b[q].x;  acc.y += ca * b[q].y;
          acc.z += ca * b[q].z;  acc.w += ca * b[q].w;
        }
      }
      *(float4*)(out + outbase + (unsigned long long)(t1 * TDIM + t2)) = acc;
    }
  }
}

extern "C" void kernel_launch(void* const* d_in, const int* in_sizes, int n_in,
                              void* d_out, int out_size, void* d_ws, size_t ws_size,
                              hipStream_t stream) {
  (void)in_sizes; (void)n_in; (void)d_ws; (void)ws_size;
  const int nrows = out_size / (TDIM * TDIM);   // = 2416 for L=7, T=128
  cg_kernel<<<nrows, 256, 0, stream>>>(d_in[0], d_in[1], d_out);
}

// Round 5
// 173.380 us; speedup vs baseline: 1.0262x; 1.0262x over previous
//
#include <hip/hip_runtime.h>

#define TDIM 128

__host__ __device__ inline int trivalid(int l, int l1, int l2) {
  int d = l1 - l2; if (d < 0) d = -d;
  return (l >= d && l <= l1 + l2) ? 1 : 0;
}

__device__ __forceinline__ float u2f(unsigned int u) {
  union { unsigned int u; float f; } w; w.u = u; return w.f;
}
__device__ __forceinline__ float bf2f(unsigned short v) {
  return u2f(((unsigned int)v) << 16);
}
__device__ __forceinline__ unsigned short f2bf(float x) {
  union { float f; unsigned int u; } w; w.f = x;
  unsigned int u = w.u;
  u += 0x7fffu + ((u >> 16) & 1u);   // round-to-nearest-even
  return (unsigned short)(u >> 16);
}

// One block per output row. Row r -> (l, m, pair p=(l1,l2));
// out[r*16384 + t1*128 + t2] = sum_{m1} C[k,i,j] * clms[i,t1] * clms[j,t2]
// Structure identical to the verified round-3 kernel; only the occupancy
// hint changed: (256,2) -> (256,4). LDS 32.3 KB allows 4 blocks/CU; live
// registers (~100 VGPR) fit the 128-VGPR cap for 4 waves/EU.
__global__ __launch_bounds__(256, 4)
void cg_kernel(const void* __restrict__ clms_raw,
               const void* __restrict__ C_raw,
               void* __restrict__ out_raw) {
  __shared__ float sc[64 * TDIM];   // 32 KB: full clms upcast/copied to f32
  __shared__ float scoef[16];

  const int tid = threadIdx.x;

  // ---- dtype sniff (same result in every thread/block) ----
  const unsigned int* cw = (const unsigned int*)clms_raw;
  int cnt_bf = 0;
  #pragma unroll
  for (int i = 0; i < 32; ++i) {
    unsigned int e = (cw[i] >> 7) & 0xFFu;
    cnt_bf += (e >= 110u && e <= 135u) ? 1 : 0;
  }
  const bool in_bf16 = (cnt_bf >= 16);
  const bool c_bf16 = ((*(const unsigned int*)C_raw) & 0xffffu) == 0x3f80u;

  if (tid < 16) scoef[tid] = 0.0f;

  // ---- stage clms into LDS as f32 ----
  if (in_bf16) {
    const uint4* cl4 = (const uint4*)clms_raw;   // 8192 bf16 = 1024 uint4
    #pragma unroll
    for (int it = 0; it < 4; ++it) {
      int v = tid + it * 256;
      uint4 w = cl4[v];
      float4* dst = (float4*)&sc[v * 8];
      float4 d0, d1;
      d0.x = u2f(w.x << 16); d0.y = u2f(w.x & 0xffff0000u);
      d0.z = u2f(w.y << 16); d0.w = u2f(w.y & 0xffff0000u);
      d1.x = u2f(w.z << 16); d1.y = u2f(w.z & 0xffff0000u);
      d1.z = u2f(w.w << 16); d1.w = u2f(w.w & 0xffff0000u);
      dst[0] = d0; dst[1] = d1;
    }
  } else {
    const float4* cf4 = (const float4*)clms_raw; // 8192 f32 = 2048 float4
    float4* sc4 = (float4*)sc;
    #pragma unroll
    for (int it = 0; it < 8; ++it) {
      int v = tid + it * 256;
      sc4[v] = cf4[v];
    }
  }

  // ---- decode blockIdx -> (l, m, l1, l2); uniform ----
  const int r = blockIdx.x;
  int rem = r, l = 0, cnt = 0;
  for (l = 0; l < 8; ++l) {
    cnt = 0;
    for (int a = 0; a < 8; ++a)
      for (int b = 0; b < 8; ++b) cnt += trivalid(l, a, b);
    int rows = (2 * l + 1) * cnt;
    if (rem < rows) break;
    rem -= rows;
  }
  const int mi = rem / cnt;          // m + l
  const int p  = rem - mi * cnt;     // pair index (l1-major order)
  const int m  = mi - l;
  int l1 = 0, l2 = 0;
  {
    int q = 0; bool done = false;
    for (int a = 0; a < 8 && !done; ++a)
      for (int b = 0; b < 8; ++b) {
        if (trivalid(l, a, b)) {
          if (q == p) { l1 = a; l2 = b; done = true; break; }
          ++q;
        }
      }
  }

  int m1lo = (-l1 > m - l2) ? -l1 : (m - l2);
  int m1hi = ( l1 < m + l2) ?  l1 : (m + l2);
  const int nnz = m1hi - m1lo + 1;   // 1..15

  // ---- stage CG coefficients for this row ----
  if (tid < nnz) {
    int m1 = m1lo + tid;
    int m2 = m - m1;
    int i  = l1 * (l1 + 1) + m1;
    int j  = l2 * (l2 + 1) + m2;
    int k  = l  * (l  + 1) + m;
    int ci = ((k * 64) + i) * 64 + j;
    scoef[tid] = c_bf16 ? bf2f(((const unsigned short*)C_raw)[ci])
                        : ((const float*)C_raw)[ci];
  }
  __syncthreads();

  float creg[15];
  #pragma unroll
  for (int q = 0; q < 15; ++q) creg[q] = scoef[q];   // q>=nnz -> 0.0f

  const int tx = tid & 31;
  const int ty = tid >> 5;
  const int t2 = tx * 4;
  const int i0 = l1 * (l1 + 1) + m1lo;           // A rows: i0+q
  const int j0 = l2 * (l2 + 1) + m - m1lo;       // B rows: j0-q

  // Precompute CLAMPED row offsets so any access (even speculated) is in-range.
  int arow[15], brow[15];
  #pragma unroll
  for (int q = 0; q < 15; ++q) {
    int qc = (q < nnz) ? q : 0;
    arow[q] = (i0 + qc) * TDIM;
    brow[q] = (j0 - qc) * TDIM;
  }

  float4 b[15];
  #pragma unroll
  for (int q = 0; q < 15; ++q) b[q] = *(const float4*)&sc[brow[q] + t2];

  const unsigned long long outbase = (unsigned long long)r * (TDIM * TDIM);

  if (in_bf16) {
    unsigned short* out = (unsigned short*)out_raw;
    #pragma unroll 4
    for (int s = 0; s < 16; ++s) {
      const int t1 = ty + 8 * s;
      float4 acc = make_float4(0.f, 0.f, 0.f, 0.f);
      #pragma unroll
      for (int q = 0; q < 15; ++q) {
        if (q < nnz) {                    // nnz uniform -> scalar branch
          float ca = creg[q] * sc[arow[q] + t1];
          acc.x += ca * b[q].x;  acc.y += ca * b[q].y;
          acc.z += ca * b[q].z;  acc.w += ca * b[q].w;
        }
      }
      ushort4 o;
      o.x = f2bf(acc.x); o.y = f2bf(acc.y);
      o.z = f2bf(acc.z); o.w = f2bf(acc.w);
      *(ushort4*)(out + outbase + (unsigned long long)(t1 * TDIM + t2)) = o;
    }
  } else {
    float* out = (float*)out_raw;
    #pragma unroll 4
    for (int s = 0; s < 16; ++s) {
      const int t1 = ty + 8 * s;
      float4 acc = make_float4(0.f, 0.f, 0.f, 0.f);
      #pragma unroll
      for (int q = 0; q < 15; ++q) {
        if (q < nnz) {
          float ca = creg[q] * sc[arow[q] + t1];
          acc.x += ca * b[q].x;  acc.y += ca * b[q].y;
          acc.z += ca * b[q].z;  acc.w += ca * b[q].w;
        }
      }
      *(float4*)(out + outbase + (unsigned long long)(t1 * TDIM + t2)) = acc;
    }
  }
}

extern "C" void kernel_launch(void* const* d_in, const int* in_sizes, int n_in,
                              void* d_out, int out_size, void* d_ws, size_t ws_size,
                              hipStream_t stream) {
  (void)in_sizes; (void)n_in; (void)d_ws; (void)ws_size;
  const int nrows = out_size / (TDIM * TDIM);   // 2416 for L=7, T=128
  cg_kernel<<<nrows, 256, 0, stream>>>(d_in[0], d_in[1], d_out);
}